// Round 16
// baseline (5810.831 us; speedup 1.0000x reference)
//
#include <hip/hip_runtime.h>
#include <hip/hip_bf16.h>
#include <cstdint>
#include <cstddef>

// Autoformer forward, MI355X. Round 16: r15 (passing) with FFN M-chunked at
// 29696 rows so the packed hidden chunk (122 MB) stays Infinity-Cache-resident:
// FFN1 writes absorbed by MALL, FFN2 reads at L3 BW. No kernel changes.
#define B_   1024
#define LE   96
#define LD   116
#define DM   256
#define DFF  1024

typedef __attribute__((ext_vector_type(8))) short bf16x8;
typedef __attribute__((ext_vector_type(4))) float f32x4;

static __device__ __forceinline__ unsigned short f2b(float f) {
  __hip_bfloat16 h = __float2bfloat16(f);
  return *reinterpret_cast<unsigned short*>(&h);
}
static __device__ __forceinline__ float asf(unsigned int u) { return __uint_as_float(u); }
static __device__ __forceinline__ void split1(float f, unsigned short& h, unsigned short& l) {
  h = f2b(f);
  l = f2b(f - asf((unsigned int)h << 16));
}
static __device__ __forceinline__ unsigned int pck(float f) {
  unsigned short h, l; split1(f, h, l);
  return ((unsigned int)h << 16) | l;
}
static __device__ __forceinline__ float unp(unsigned int p) {
  return asf(p & 0xFFFF0000u) + asf(p << 16);
}
static __device__ __forceinline__ void split8(float4 a, float4 b, uint4& h4, uint4& l4) {
  float f[8] = {a.x, a.y, a.z, a.w, b.x, b.y, b.z, b.w};
  unsigned int hp[4], lp[4];
#pragma unroll
  for (int j = 0; j < 4; ++j) {
    unsigned short h0, l0, h1, l1;
    split1(f[2 * j], h0, l0);
    split1(f[2 * j + 1], h1, l1);
    hp[j] = (unsigned int)h0 | ((unsigned int)h1 << 16);
    lp[j] = (unsigned int)l0 | ((unsigned int)l1 << 16);
  }
  h4 = make_uint4(hp[0], hp[1], hp[2], hp[3]);
  l4 = make_uint4(lp[0], lp[1], lp[2], lp[3]);
}
static __device__ __forceinline__ void unpack8(uint4 a, uint4 b, uint4& h, uint4& l) {
  h.x = (a.y & 0xFFFF0000u) | (a.x >> 16);
  l.x = (a.y << 16) | (a.x & 0xFFFFu);
  h.y = (a.w & 0xFFFF0000u) | (a.z >> 16);
  l.y = (a.w << 16) | (a.z & 0xFFFFu);
  h.z = (b.y & 0xFFFF0000u) | (b.x >> 16);
  l.z = (b.y << 16) | (b.x & 0xFFFFu);
  h.w = (b.w & 0xFFFF0000u) | (b.z >> 16);
  l.w = (b.w << 16) | (b.z & 0xFFFFu);
}

typedef const __attribute__((address_space(1))) void* gas_ptr;
typedef __attribute__((address_space(3))) void* las_ptr;
static __device__ __forceinline__ void gload16(const void* g, void* l) {
  __builtin_amdgcn_global_load_lds((gas_ptr)g, (las_ptr)l, 16, 0, 0);
}

// ---------------- workspace ----------------
#define NE_ ((size_t)B_ * LE * DM)
#define ND_ ((size_t)B_ * LD * DM)
#define NS_ ((size_t)B_ * LD * 5)
#define NW_ ((size_t)B_ * 16)
#define WBF_ 3145728
#define MCH_ 29696

static constexpr size_t o_enc   = 0;
static constexpr size_t o_dec   = o_enc   + NE_ * 4;
static constexpr size_t o_q     = o_dec   + ND_ * 4;
static constexpr size_t o_kbuf  = o_q     + ND_ * 4;
static constexpr size_t o_yup   = o_kbuf  + ND_ * 4;   // packed [M][512]
static constexpr size_t o_qxp   = o_yup   + ND_ * 8;   // packed cross-Q [MD][256]
static constexpr size_t o_gthp  = o_qxp   + ND_ * 4;   // packed cross gather out
static constexpr size_t o_hidp  = o_gthp  + ND_ * 4;   // packed FFN hidden [MCH][1024]
static constexpr size_t o_spad  = o_hidp  + (size_t)MCH_ * DFF * 4;
static constexpr size_t o_trend = o_spad  + NS_ * 4;
static constexpr size_t o_wtop  = o_trend + NS_ * 4;
static constexpr size_t o_dtop  = o_wtop  + NW_ * 4;
static constexpr size_t o_bias  = o_dtop  + NW_ * 4;   // 2048 floats
static constexpr size_t o_whi   = o_bias  + 2048 * 4;
static constexpr size_t o_wlo   = o_whi   + (size_t)WBF_ * 2;
static constexpr size_t WS_TOTAL = o_wlo  + (size_t)WBF_ * 2;

__device__ __align__(256) unsigned char g_ws[WS_TOTAL];

static __host__ __device__ constexpr size_t enc_base(int i) { return (size_t)i * 655360; }
static __host__ __device__ constexpr size_t dec_base(int i) { return 1310720 + (size_t)i * 917504; }

// ---------------- weight split cast ----------------
__global__ __launch_bounds__(256)
void k_cast_split(const float* __restrict__ in, unsigned short* __restrict__ hi,
                  unsigned short* __restrict__ lo, int n) {
  int i = (blockIdx.x * 256 + threadIdx.x) * 4;
  if (i < n) {
    float4 v = *(const float4*)(in + i);
    unsigned int hp[2], lp[2];
    float f[4] = {v.x, v.y, v.z, v.w};
#pragma unroll
    for (int j = 0; j < 2; ++j) {
      unsigned short h0, l0, h1, l1;
      split1(f[2 * j], h0, l0);
      split1(f[2 * j + 1], h1, l1);
      hp[j] = (unsigned int)h0 | ((unsigned int)h1 << 16);
      lp[j] = (unsigned int)l0 | ((unsigned int)l1 << 16);
    }
    *(uint2*)(hi + i) = make_uint2(hp[0], hp[1]);
    *(uint2*)(lo + i) = make_uint2(lp[0], lp[1]);
  }
}

// ---------------- weight composition ----------------
__global__ __launch_bounds__(256)
void k_compose_qk(const float* __restrict__ Wq, const float* __restrict__ Wk,
                  unsigned short* __restrict__ hi, unsigned short* __restrict__ lo) {
  int j = blockIdx.x, i = threadIdx.x;
  __shared__ float wkc[256];
  wkc[i] = Wk[i * 256 + j];
  __syncthreads();
  float s = 0.f;
  for (int o = 0; o < 256; ++o) s += Wq[o * 256 + i] * wkc[o];
  unsigned short h, l; split1(s, h, l);
  hi[j * 256 + i] = h; lo[j * 256 + i] = l;
}
__global__ __launch_bounds__(256)
void k_compose_vo(const float* __restrict__ Wv, const float* __restrict__ Wo,
                  unsigned short* __restrict__ hi, unsigned short* __restrict__ lo) {
  int o2 = blockIdx.x, i = threadIdx.x;
  __shared__ float woc[256];
  woc[i] = Wo[o2 * 256 + i];
  __syncthreads();
  float s = 0.f;
  for (int c = 0; c < 256; ++c) s += woc[c] * Wv[c * 256 + i];
  unsigned short h, l; split1(s, h, l);
  hi[o2 * 256 + i] = h; lo[o2 * 256 + i] = l;
}
__global__ __launch_bounds__(256)
void k_bout(const float* __restrict__ Wo, const float* __restrict__ bv,
            const float* __restrict__ bo, float* __restrict__ dst) {
  int o2 = threadIdx.x;
  __shared__ float bvs[256];
  bvs[o2] = bv[o2];
  __syncthreads();
  float s = bo[o2];
  for (int c = 0; c < 256; ++c) s += Wo[o2 * 256 + c] * bvs[c];
  dst[o2] = s;
}
__global__ __launch_bounds__(256)
void k_cat2(const float* __restrict__ a, const float* __restrict__ b, float* __restrict__ dst) {
  int t = threadIdx.x;
  dst[t] = a[t];
  dst[256 + t] = b[t];
}

// ---------------- preprocess ----------------
__global__ __launch_bounds__(128)
void k_pre(const float* __restrict__ x, float* __restrict__ spad, float* __restrict__ trend) {
  int b = blockIdx.x;
  __shared__ float xs[LE * 5];
  __shared__ float mx[5];
  const float* xb = x + (size_t)b * LE * 5;
  for (int i = threadIdx.x; i < LE * 5; i += 128) xs[i] = xb[i];
  __syncthreads();
  if (threadIdx.x < 5) {
    float s = 0.f;
    for (int t = 0; t < LE; ++t) s += xs[t * 5 + threadIdx.x];
    mx[threadIdx.x] = s * (1.f / 96.f);
  }
  __syncthreads();
  float* spb = spad + (size_t)b * LD * 5;
  float* trb = trend + (size_t)b * LD * 5;
  for (int i = threadIdx.x; i < LE * 5; i += 128) {
    int t = i / 5, c = i % 5;
    float s = 0.f;
    for (int d = -12; d <= 12; ++d) {
      int tt = t + d; tt = tt < 0 ? 0 : (tt > LE - 1 ? LE - 1 : tt);
      s += xs[tt * 5 + c];
    }
    float m = s * (1.f / 25.f);
    trb[t * 5 + c] = m;
    spb[(t + 20) * 5 + c] = xs[i] - m;
  }
  for (int i = threadIdx.x; i < 20 * 5; i += 128) {
    int t = i / 5, c = i % 5;
    spb[t * 5 + c] = 0.f;
    trb[(LE + t) * 5 + c] = mx[c];
  }
}

// ---------------- circular 3-tap conv (f32 out) ----------------
__global__ __launch_bounds__(256)
void k_conv3(const float* __restrict__ xin, const float* __restrict__ W,
             float* __restrict__ out, int L) {
  int b = blockIdx.x, o = threadIdx.x;
  __shared__ float xs[LD * 5];
  const float* xb = xin + (size_t)b * L * 5;
  for (int i = o; i < L * 5; i += 256) xs[i] = xb[i];
  __syncthreads();
  float w[15];
#pragma unroll
  for (int j = 0; j < 15; ++j) w[j] = W[o * 15 + j];
  size_t ob = (size_t)b * L * DM + o;
  for (int l = 0; l < L; ++l) {
    int lm = (l == 0) ? L - 1 : l - 1;
    int lp = (l == L - 1) ? 0 : l + 1;
    float acc = 0.f;
#pragma unroll
    for (int c = 0; c < 5; ++c)
      acc += xs[lm * 5 + c] * w[c * 3] + xs[l * 5 + c] * w[c * 3 + 1] + xs[lp * 5 + c] * w[c * 3 + 2];
    out[ob + (size_t)l * DM] = acc;
  }
}

// ---------------- unified MFMA GEMM, double-buffered 2-phase K-loop ----------------
// XMODE 0: X f32 (register-staged, split8). XMODE 1: X packed u32 (unpack8).
// OMODE 0: f32 C. OMODE 1: packed u32 C.
template <int XMODE, int OMODE, bool RELU>
__global__ __launch_bounds__(256)
void k_gemm_u(const float* __restrict__ Xf, const unsigned int* __restrict__ Xp,
              const unsigned short* __restrict__ Whi, const unsigned short* __restrict__ Wlo,
              const float* __restrict__ bias, float* __restrict__ Cf,
              unsigned int* __restrict__ Cp, int M, int N, int K) {
  __shared__ __align__(16) unsigned short Xh[2][4096], Xl[2][4096], Wh[2][4096], Wl[2][4096];
  const int nwg = gridDim.x, bid = blockIdx.x;
  const int wg = (bid & 7) * (nwg >> 3) + (bid >> 3);   // XCD swizzle (nwg%8==0)
  const int NT = N >> 7;
  const int mt = wg / NT, nt = wg % NT;
  const int m0 = mt << 7, n0 = nt << 7;
  const int tid = threadIdx.x, lane = tid & 63, wv = tid >> 6;
  const int wm = (wv >> 1) << 6, wn = (wv & 1) << 6;

  f32x4 acc[4][4];
#pragma unroll
  for (int i = 0; i < 4; ++i)
#pragma unroll
    for (int j = 0; j < 4; ++j) acc[i][j] = (f32x4){0.f, 0.f, 0.f, 0.f};

  const int r0 = tid >> 2,        ls0 = (tid & 3) ^ ((r0 >> 1) & 3);
  const int r1 = 64 + (tid >> 2), ls1 = (tid & 3) ^ ((r1 >> 1) & 3);
  const unsigned short* wh0 = Whi + (size_t)(n0 + r0) * K + (ls0 << 3);
  const unsigned short* wh1 = Whi + (size_t)(n0 + r1) * K + (ls1 << 3);
  const unsigned short* wl0 = Wlo + (size_t)(n0 + r0) * K + (ls0 << 3);
  const unsigned short* wl1 = Wlo + (size_t)(n0 + r1) * K + (ls1 << 3);
  const int lofs0 = (tid & ~63) << 3, lofs1 = 2048 + ((tid & ~63) << 3);

  const int xrow0 = tid >> 2, xpart = tid & 3;
  const int xrow1 = 64 + xrow0;
  const int xph0 = xpart ^ ((xrow0 >> 1) & 3);
  const int xph1 = xpart ^ ((xrow1 >> 1) & 3);
  const int xo0 = xrow0 * 32 + (xph0 << 3);
  const int xo1 = xrow1 * 32 + (xph1 << 3);
  const float* xf0 = Xf + (size_t)(m0 + xrow0) * K + (xpart << 3);
  const float* xf1 = Xf + (size_t)(m0 + xrow1) * K + (xpart << 3);
  const unsigned int* xp0 = Xp + (size_t)(m0 + xrow0) * K + (xpart << 3);
  const unsigned int* xp1 = Xp + (size_t)(m0 + xrow1) * K + (xpart << 3);

  const int nsteps = K >> 5;

  auto stage = [&](int bsel, int k0) {
    gload16(wh0 + k0, &Wh[bsel][lofs0]);
    gload16(wh1 + k0, &Wh[bsel][lofs1]);
    gload16(wl0 + k0, &Wl[bsel][lofs0]);
    gload16(wl1 + k0, &Wl[bsel][lofs1]);
    uint4 h, l;
    if (XMODE == 0) {
      float4 a0 = *(const float4*)(xf0 + k0);
      float4 b0 = *(const float4*)(xf0 + k0 + 4);
      float4 a1 = *(const float4*)(xf1 + k0);
      float4 b1 = *(const float4*)(xf1 + k0 + 4);
      split8(a0, b0, h, l);
      *(uint4*)&Xh[bsel][xo0] = h; *(uint4*)&Xl[bsel][xo0] = l;
      split8(a1, b1, h, l);
      *(uint4*)&Xh[bsel][xo1] = h; *(uint4*)&Xl[bsel][xo1] = l;
    } else {
      uint4 a0 = *(const uint4*)(xp0 + k0);
      uint4 b0 = *(const uint4*)(xp0 + k0 + 4);
      uint4 a1 = *(const uint4*)(xp1 + k0);
      uint4 b1 = *(const uint4*)(xp1 + k0 + 4);
      unpack8(a0, b0, h, l);
      *(uint4*)&Xh[bsel][xo0] = h; *(uint4*)&Xl[bsel][xo0] = l;
      unpack8(a1, b1, h, l);
      *(uint4*)&Xh[bsel][xo1] = h; *(uint4*)&Xl[bsel][xo1] = l;
    }
  };

  stage(0, 0);
  __syncthreads();

  for (int step = 0; step < nsteps; ++step) {
    int cur = step & 1;
    if (step + 1 < nsteps) stage(cur ^ 1, (step + 1) << 5);
    bf16x8 ah[4], al[4], bh[4], bl[4];
#pragma unroll
    for (int i = 0; i < 4; ++i) {
      int ra = wm + i * 16 + (lane & 15);
      int sa = (lane >> 4) ^ ((ra >> 1) & 3);
      ah[i] = *(const bf16x8*)(&Xh[cur][ra * 32 + (sa << 3)]);
      al[i] = *(const bf16x8*)(&Xl[cur][ra * 32 + (sa << 3)]);
      int rb = wn + i * 16 + (lane & 15);
      int sb = (lane >> 4) ^ ((rb >> 1) & 3);
      bh[i] = *(const bf16x8*)(&Wh[cur][rb * 32 + (sb << 3)]);
      bl[i] = *(const bf16x8*)(&Wl[cur][rb * 32 + (sb << 3)]);
    }
#pragma unroll
    for (int i = 0; i < 4; ++i)
#pragma unroll
      for (int j = 0; j < 4; ++j) {
        acc[i][j] = __builtin_amdgcn_mfma_f32_16x16x32_bf16(ah[i], bh[j], acc[i][j], 0, 0, 0);
        acc[i][j] = __builtin_amdgcn_mfma_f32_16x16x32_bf16(al[i], bh[j], acc[i][j], 0, 0, 0);
        acc[i][j] = __builtin_amdgcn_mfma_f32_16x16x32_bf16(ah[i], bl[j], acc[i][j], 0, 0, 0);
      }
    __syncthreads();
  }

  const int col_base = n0 + wn + (lane & 15);
  const int row_base = m0 + wm + ((lane >> 4) << 2);
#pragma unroll
  for (int j = 0; j < 4; ++j) {
    int col = col_base + j * 16;
    float bv = bias ? bias[col] : 0.f;
#pragma unroll
    for (int i = 0; i < 4; ++i) {
      int rb2 = row_base + i * 16;
#pragma unroll
      for (int q = 0; q < 4; ++q) {
        float o = acc[i][j][q] + bv;
        if (RELU) o = fmaxf(o, 0.f);
        size_t idx = (size_t)(rb2 + q) * N + col;
        if (OMODE == 0) Cf[idx] = o;
        else            Cp[idx] = pck(o);
      }
    }
  }
}

// ---------------- corr (MFMA Gram, per-side f32/packed) + fused top-k/softmax ----------------
template <int QM, int KM>   // 0 = f32 input, 1 = packed u32 input
__global__ __launch_bounds__(256)
void k_corr2(const float* __restrict__ Qf, const unsigned int* __restrict__ Qp, int sq,
             const float* __restrict__ Kf, const unsigned int* __restrict__ Kpk, int sk,
             float* __restrict__ wout, int* __restrict__ dout,
             int L, int S, int TK) {
  __shared__ __align__(16) unsigned char smem[65536];
  unsigned short* qh = (unsigned short*)smem;   // [128][64]
  unsigned short* ql = qh + 8192;
  unsigned short* kh = ql + 8192;
  unsigned short* kl = kh + 8192;
  float* G = (float*)smem;                      // [128][128] overlays after K-loop
  int b = blockIdx.x, tid = threadIdx.x, lane = tid & 63, wv = tid >> 6;
  int wm = (wv >> 1) << 6, wn = (wv & 1) << 6;
  const float*        Qfb = Qf  + (size_t)b * L * sq;
  const unsigned int* Qpb = Qp  + (size_t)b * L * sq;
  const float*        Kfb = Kf  + (size_t)b * S * sk;
  const unsigned int* Kpb = Kpk + (size_t)b * S * sk;
  f32x4 acc[4][4];
#pragma unroll
  for (int i = 0; i < 4; ++i)
#pragma unroll
    for (int j = 0; j < 4; ++j) acc[i][j] = (f32x4){0.f, 0.f, 0.f, 0.f};

  for (int c0 = 0; c0 < DM; c0 += 64) {
#pragma unroll
    for (int u = 0; u < 4; ++u) {
      int seg = (u << 8) + tid;
      int row = seg >> 3, ps = seg & 7;
      int phys = ps ^ (row & 7);
      uint4 h = make_uint4(0u, 0u, 0u, 0u), l = make_uint4(0u, 0u, 0u, 0u);
      if (row < L) {
        if (QM == 0) {
          float4 a = *(const float4*)(Qfb + (size_t)row * sq + c0 + (ps << 3));
          float4 c = *(const float4*)(Qfb + (size_t)row * sq + c0 + (ps << 3) + 4);
          split8(a, c, h, l);
        } else {
          uint4 a = *(const uint4*)(Qpb + (size_t)row * sq + c0 + (ps << 3));
          uint4 c = *(const uint4*)(Qpb + (size_t)row * sq + c0 + (ps << 3) + 4);
          unpack8(a, c, h, l);
        }
      }
      *(uint4*)(qh + row * 64 + (phys << 3)) = h;
      *(uint4*)(ql + row * 64 + (phys << 3)) = l;
      h = make_uint4(0u, 0u, 0u, 0u); l = make_uint4(0u, 0u, 0u, 0u);
      if (row < S) {
        if (KM == 0) {
          float4 a = *(const float4*)(Kfb + (size_t)row * sk + c0 + (ps << 3));
          float4 c = *(const float4*)(Kfb + (size_t)row * sk + c0 + (ps << 3) + 4);
          split8(a, c, h, l);
        } else {
          uint4 a = *(const uint4*)(Kpb + (size_t)row * sk + c0 + (ps << 3));
          uint4 c = *(const uint4*)(Kpb + (size_t)row * sk + c0 + (ps << 3) + 4);
          unpack8(a, c, h, l);
        }
      }
      *(uint4*)(kh + row * 64 + (phys << 3)) = h;
      *(uint4*)(kl + row * 64 + (phys << 3)) = l;
    }
    __syncthreads();
#pragma unroll
    for (int ks = 0; ks < 2; ++ks) {
      bf16x8 aqh[4], aql[4], bkh[4], bkl[4];
#pragma unroll
      for (int i = 0; i < 4; ++i) {
        int ra = wm + i * 16 + (lane & 15);
        int sa = ((ks << 2) + (lane >> 4)) ^ (ra & 7);
        aqh[i] = *(const bf16x8*)(qh + ra * 64 + (sa << 3));
        aql[i] = *(const bf16x8*)(ql + ra * 64 + (sa << 3));
        int rb = wn + i * 16 + (lane & 15);
        int sb = ((ks << 2) + (lane >> 4)) ^ (rb & 7);
        bkh[i] = *(const bf16x8*)(kh + rb * 64 + (sb << 3));
        bkl[i] = *(const bf16x8*)(kl + rb * 64 + (sb << 3));
      }
#pragma unroll
      for (int i = 0; i < 4; ++i)
#pragma unroll
        for (int j = 0; j < 4; ++j) {
          acc[i][j] = __builtin_amdgcn_mfma_f32_16x16x32_bf16(aqh[i], bkh[j], acc[i][j], 0, 0, 0);
          acc[i][j] = __builtin_amdgcn_mfma_f32_16x16x32_bf16(aql[i], bkh[j], acc[i][j], 0, 0, 0);
          acc[i][j] = __builtin_amdgcn_mfma_f32_16x16x32_bf16(aqh[i], bkl[j], acc[i][j], 0, 0, 0);
        }
    }
    __syncthreads();
  }
#pragma unroll
  for (int i = 0; i < 4; ++i)
#pragma unroll
    for (int j = 0; j < 4; ++j)
#pragma unroll
      for (int q = 0; q < 4; ++q)
        G[(wm + i * 16 + ((lane >> 4) << 2) + q) * 128 + wn + j * 16 + (lane & 15)] = acc[i][j][q];
  __syncthreads();
  float s = 0.f;
  if (tid < L) {
    for (int t = 0; t < L; ++t) {
      int r = t - tid; if (r < 0) r += L;
      s += G[t * 128 + r];
    }
    s *= (1.f / 256.f);
  }
  __syncthreads();

  float* vals = (float*)smem;
  float* rv   = vals + 128;
  int*   ri   = (int*)(rv + 128);
  float* selv = (float*)(ri + 128);
  int*   seli = (int*)(selv + 16);
  if (tid < 128) vals[tid] = (tid < L) ? s : -3e38f;
  __syncthreads();
  for (int it = 0; it < TK; ++it) {
    if (tid < 128) { rv[tid] = vals[tid]; ri[tid] = tid; }
    __syncthreads();
    for (int off = 64; off >= 1; off >>= 1) {
      if (tid < off) {
        float v2 = rv[tid + off]; int i2 = ri[tid + off];
        if (v2 > rv[tid] || (v2 == rv[tid] && i2 < ri[tid])) { rv[tid] = v2; ri[tid] = i2; }
      }
      __syncthreads();
    }
    if (tid == 0) { selv[it] = rv[0]; seli[it] = ri[0]; vals[ri[0]] = -3e38f; }
    __syncthreads();
  }
  if (tid == 0) {
    float mxv = selv[0];
    float e[16]; float sum = 0.f;
    for (int j = 0; j < TK; ++j) { e[j] = expf(selv[j] - mxv); sum += e[j]; }
    float inv = 1.f / sum;
    for (int j = 0; j < TK; ++j) {
      wout[(size_t)b * 16 + j] = e[j] * inv;
      dout[(size_t)b * 16 + j] = seli[j];
    }
  }
}

// ---------------- gather: 8 l/block, packed V in, XCD-affine ----------------
template <int SELF>
__global__ __launch_bounds__(256)
void k_gather5(const unsigned int* __restrict__ V, int sv, const float* __restrict__ wtop,
               const int* __restrict__ dtop, float* __restrict__ outf,
               unsigned int* __restrict__ outp, const float* __restrict__ bout,
               int L, int S, int TK, int G8) {
  int p = blockIdx.x;
  int xcd = p & 7, q8 = p >> 3;
  int lg = q8 % G8;
  int b = ((q8 / G8) << 3) + xcd;
  __shared__ float wsm[16];
  __shared__ int   dsm[16];
  __shared__ float bsm[256];
  if (threadIdx.x < TK) {
    wsm[threadIdx.x] = wtop[(size_t)b * 16 + threadIdx.x];
    dsm[threadIdx.x] = dtop[(size_t)b * 16 + threadIdx.x];
  }
  if (SELF) bsm[threadIdx.x] = bout[threadIdx.x];
  __syncthreads();
  int wv = threadIdx.x >> 6, lane = threadIdx.x & 63;
  int c4 = lane << 2;
  const unsigned int* Vb = V + (size_t)b * S * sv + c4;
  size_t ob = (size_t)b * L * DM + c4;
#pragma unroll
  for (int u = 0; u < 2; ++u) {
    int l = (lg << 3) + (wv << 1) + u;
    if (l < L) {
      float a0 = 0.f, a1 = 0.f, a2 = 0.f, a3 = 0.f;
      for (int j = 0; j < TK; ++j) {
        int r = l + dsm[j]; if (r >= L) r -= L;
        if (r < S) {
          uint4 v = *(const uint4*)(Vb + (size_t)r * sv);
          float w = wsm[j];
          a0 += w * unp(v.x); a1 += w * unp(v.y); a2 += w * unp(v.z); a3 += w * unp(v.w);
        }
      }
      if (SELF) {
        float4 o;
        o.x = a0 + bsm[c4];     o.y = a1 + bsm[c4 + 1];
        o.z = a2 + bsm[c4 + 2]; o.w = a3 + bsm[c4 + 3];
        *(float4*)(outf + ob + (size_t)l * DM) = o;
      } else {
        uint4 o; o.x = pck(a0); o.y = pck(a1); o.z = pck(a2); o.w = pck(a3);
        *(uint4*)(outp + ob + (size_t)l * DM) = o;
      }
    }
  }
}

// ---------------- series_decomp: f32 only ----------------
template <int MOUT>
__global__ __launch_bounds__(128)
void k_decomp(const float* __restrict__ X, const float* __restrict__ Y,
              float* __restrict__ out, float* __restrict__ mout, int L) {
  int b = blockIdx.x >> 2, qd = blockIdx.x & 3;
  __shared__ float tmp[LD * 64];
  size_t base = (size_t)b * L * DM + qd * 64;
  for (int i = threadIdx.x; i < L * 64; i += 128) {
    int t = i >> 6, cc = i & 63;
    size_t gi = base + (size_t)t * DM + cc;
    tmp[i] = X[gi] + Y[gi];
  }
  __syncthreads();
  int c = threadIdx.x & 63, th = threadIdx.x >> 6;
  int half = L >> 1;
  int t0 = th * half, t1 = t0 + half;
  float s = 0.f;
  for (int d = -12; d <= 12; ++d) {
    int t2 = t0 + d; t2 = t2 < 0 ? 0 : (t2 > L - 1 ? L - 1 : t2);
    s += tmp[t2 * 64 + c];
  }
  for (int t = t0; t < t1; ++t) {
    float m = s * (1.f / 25.f);
    size_t gi = base + (size_t)t * DM + c;
    out[gi] = tmp[t * 64 + c] - m;
    if (MOUT) mout[gi] = m;
    int ai = t + 13; if (ai > L - 1) ai = L - 1;
    int si = t - 12; if (si < 0) si = 0;
    s += tmp[ai * 64 + c] - tmp[si * 64 + c];
  }
}

// ---------------- my_layernorm (f32 only) ----------------
__global__ __launch_bounds__(256)
void k_lnorm(const float* __restrict__ X, const float* __restrict__ g,
             float* __restrict__ out, int L) {
  int b = blockIdx.x;
  __shared__ float mu_s[LD], inv_s[LD];
  size_t base = (size_t)b * L * DM;
  int wv = threadIdx.x >> 6, lane = threadIdx.x & 63;
  for (int t = wv; t < L; t += 4) {
    float s = 0.f, s2 = 0.f;
#pragma unroll
    for (int qd = 0; qd < 4; ++qd) {
      float val = X[base + (size_t)t * DM + lane + 64 * qd];
      s += val; s2 += val * val;
    }
    for (int off = 32; off; off >>= 1) { s += __shfl_xor(s, off); s2 += __shfl_xor(s2, off); }
    if (lane == 0) {
      float mu = s * (1.f / 256.f);
      mu_s[t] = mu;
      inv_s[t] = rsqrtf(s2 * (1.f / 256.f) - mu * mu + 1e-5f);
    }
  }
  __syncthreads();
  int c = threadIdx.x;
  float gc = g[c];
  float sm = 0.f;
  for (int t = 0; t < L; ++t) sm += (X[base + (size_t)t * DM + c] - mu_s[t]) * inv_s[t];
  float mn = sm / (float)L;
  for (int t = 0; t < L; ++t) {
    float xn = (X[base + (size_t)t * DM + c] - mu_s[t]) * inv_s[t];
    out[base + (size_t)t * DM + c] = gc * (xn - mn);
  }
}

// ---------------- trend conv: rolling single-read, 1 block/batch ----------------
__global__ __launch_bounds__(256)
void k_trendconv(const float* __restrict__ T, const float* __restrict__ Wt,
                 float* __restrict__ trend, int L) {
  int b = blockIdx.x;
  int tid = threadIdx.x, wv = tid >> 6, lane = tid & 63;
  int c0 = lane << 2;
  float w[5][3][4];
#pragma unroll
  for (int o = 0; o < 5; ++o)
#pragma unroll
    for (int k = 0; k < 4; ++k) {
      w[o][0][k] = Wt[o * 768 + (c0 + k) * 3 + 0];
      w[o][1][k] = Wt[o * 768 + (c0 + k) * 3 + 1];
      w[o][2][k] = Wt[o * 768 + (c0 + k) * 3 + 2];
    }
  size_t base = (size_t)b * L * DM;
  int chunk = (L + 3) >> 2;
  int l0 = wv * chunk;
  int cnt = (L - l0 < chunk) ? (L - l0) : chunk;
  if (cnt <= 0) return;
  int lmi = (l0 == 0) ? L - 1 : l0 - 1;
  float4 pm = *(const float4*)(T + base + (size_t)lmi * DM + c0);
  float4 p0 = *(const float4*)(T + base + (size_t)l0  * DM + c0);
  for (int i = 0; i < cnt; ++i) {
    int l = l0 + i;
    int lp = (l == L - 1) ? 0 : l + 1;
    float4 pp = *(const float4*)(T + base + (size_t)lp * DM + c0);
    float fm[4] = {pm.x, pm.y, pm.z, pm.w};
    float f0[4] = {p0.x, p0.y, p0.z, p0.w};
    float fp[4] = {pp.x, pp.y, pp.z, pp.w};
    float acc[5];
#pragma unroll
    for (int o = 0; o < 5; ++o) {
      float a = 0.f;
#pragma unroll
      for (int k = 0; k < 4; ++k)
        a += fm[k] * w[o][0][k] + f0[k] * w[o][1][k] + fp[k] * w[o][2][k];
      acc[o] = a;
    }
#pragma unroll
    for (int off = 32; off; off >>= 1)
#pragma unroll
      for (int o = 0; o < 5; ++o) acc[o] += __shfl_xor(acc[o], off);
    if (lane == 0) {
#pragma unroll
      for (int o = 0; o < 5; ++o)
        trend[((size_t)b * L + l) * 5 + o] += acc[o];
    }
    pm = p0; p0 = pp;
  }
}

// ---------------- final head ----------------
__global__ __launch_bounds__(256)
void k_final(const float* __restrict__ dec, const float* __restrict__ trend,
             const float* __restrict__ projW, const float* __restrict__ projb,
             const float* __restrict__ bng, const float* __restrict__ bnb,
             const float* __restrict__ bnrm, const float* __restrict__ bnrv,
             const float* __restrict__ fcW, const float* __restrict__ fcb,
             float* __restrict__ outp) {
  int b = blockIdx.x, c = threadIdx.x;
  __shared__ float red[5][256];
  float xv = dec[((size_t)b * LD + (LD - 1)) * DM + c];
#pragma unroll
  for (int o = 0; o < 5; ++o) red[o][c] = xv * projW[o * 256 + c];
  __syncthreads();
  for (int off = 128; off >= 1; off >>= 1) {
    if (c < off) {
#pragma unroll
      for (int o = 0; o < 5; ++o) red[o][c] += red[o][c + off];
    }
    __syncthreads();
  }
  if (c == 0) {
    float acc = fcb[0];
    for (int j = 0; j < 20; ++j) {
      int m5 = j % 5;
      float last = trend[((size_t)b * LD + (LD - 1)) * 5 + m5] + red[m5][0] + projb[m5];
      float h = (last - bnrm[j]) * rsqrtf(bnrv[j] + 1e-5f) * bng[j] + bnb[j];
      acc += h * fcW[j];
    }
    outp[b] = acc;
  }
}

// ================================ host ================================
extern "C" void kernel_launch(void* const* d_in, const int* in_sizes, int n_in,
                              void* d_out, int out_size, void* d_ws, size_t ws_size,
                              hipStream_t stream) {
  const float* x      = (const float*)d_in[0];
  const float* we_enc = (const float*)d_in[1];
  const float* we_dec = (const float*)d_in[2];
  const float* enc_Wq = (const float*)d_in[3];
  const float* enc_bq = (const float*)d_in[4];
  const float* enc_Wk = (const float*)d_in[5];
  const float* enc_bk = (const float*)d_in[6];
  const float* enc_Wv = (const float*)d_in[7];
  const float* enc_bv = (const float*)d_in[8];
  const float* enc_Wo = (const float*)d_in[9];
  const float* enc_bo = (const float*)d_in[10];
  const float* enc_W1 = (const float*)d_in[11];
  const float* enc_W2 = (const float*)d_in[12];
  const float* enc_g  = (const float*)d_in[13];
  const float* sWq = (const float*)d_in[15]; const float* sbq = (const float*)d_in[16];
  const float* sWk = (const float*)d_in[17]; const float* sbk = (const float*)d_in[18];
  const float* sWv = (const float*)d_in[19]; const float* sbv = (const float*)d_in[20];
  const float* sWo = (const float*)d_in[21]; const float* sbo = (const float*)d_in[22];
  const float* cWq = (const float*)d_in[23]; const float* cbq = (const float*)d_in[24];
  const float* cWk = (const float*)d_in[25]; const float* cbk = (const float*)d_in[26];
  const float* cWv = (const float*)d_in[27]; const float* cbv = (const float*)d_in[28];
  const float* cWo = (const float*)d_in[29]; const float* cbo = (const float*)d_in[30];
  const float* dW1 = (const float*)d_in[31]; const float* dW2 = (const float*)d_in[32];
  const float* dWt = (const float*)d_in[33];
  const float* dec_g  = (const float*)d_in[34];
  const float* projW = (const float*)d_in[36]; const float* projb = (const float*)d_in[37];
  const float* bng = (const float*)d_in[38]; const float* bnb = (const float*)d_in[39];
  const float* bnrm = (const float*)d_in[40]; const float* bnrv = (const float*)d_in[41];
  const float* fcW = (const float*)d_in[42]; const float* fcb = (const float*)d_in[43];
  (void)in_sizes; (void)n_in; (void)out_size; (void)d_ws; (void)ws_size;
  float* outp = (float*)d_out;

  void* symaddr = nullptr;
  if (hipGetSymbolAddress(&symaddr, HIP_SYMBOL(g_ws)) != hipSuccess || !symaddr) return;
  unsigned char* base = (unsigned char*)symaddr;
  float* enc   = (float*)(base + o_enc);
  float* dec   = (float*)(base + o_dec);
  float* q     = (float*)(base + o_q);
  float* kbuf  = (float*)(base + o_kbuf);
  unsigned int* yup  = (unsigned int*)(base + o_yup);
  unsigned int* qxp  = (unsigned int*)(base + o_qxp);
  unsigned int* gthp = (unsigned int*)(base + o_gthp);
  unsigned int* hidp = (unsigned int*)(base + o_hidp);
  float* spad  = (float*)(base + o_spad);
  float* trend = (float*)(base + o_trend);
  float* wtop  = (float*)(base + o_wtop);
  int*   dtop  = (int*)(base + o_dtop);
  float* biasb = (float*)(base + o_bias);
  unsigned short* whi = (unsigned short*)(base + o_whi);
  unsigned short* wlo = (unsigned short*)(base + o_wlo);

  const int ME = B_ * LE;
  const int MD = B_ * LD;

  auto cast = [&](const float* s, size_t off, int n) {
    k_cast_split<<<n / 1024, 256, 0, stream>>>(s, whi + off, wlo + off, n);
  };
  for (int i = 0; i < 2; ++i) {
    size_t e = enc_base(i), d = dec_base(i);
    size_t wq = (size_t)i * 65536, wf = (size_t)i * 262144;
    size_t b_ = (size_t)i * DM;
    k_compose_qk<<<256, 256, 0, stream>>>(enc_Wq + wq, enc_Wk + wq, whi + e, wlo + e);
    k_compose_vo<<<256, 256, 0, stream>>>(enc_Wv + wq, enc_Wo + wq, whi + e + 65536, wlo + e + 65536);
    k_bout<<<1, 256, 0, stream>>>(enc_Wo + wq, enc_bv + b_, enc_bo + b_, biasb + (size_t)i * 256);
    cast(enc_W1 + wf, e + 131072, 262144);
    cast(enc_W2 + wf, e + 393216, 262144);
    k_compose_qk<<<256, 256, 0, stream>>>(sWq + wq, sWk + wq, whi + d, wlo + d);
    k_compose_vo<<<256, 256, 0, stream>>>(sWv + wq, sWo + wq, whi + d + 65536, wlo + d + 65536);
    k_bout<<<1, 256, 0, stream>>>(sWo + wq, sbv + b_, sbo + b_, biasb + (size_t)(2 + i) * 256);
    cast(cWq + wq, d + 131072, 65536);
    cast(cWk + wq, d + 196608, 65536);
    cast(cWv + wq, d + 262144, 65536);
    cast(cWo + wq, d + 327680, 65536);
    cast(dW1 + wf, d + 393216, 262144);
    cast(dW2 + wf, d + 655360, 262144);
    k_cat2<<<1, 256, 0, stream>>>(cbk + b_, cbv + b_, biasb + 1024 + (size_t)i * 512);
  }

  auto gemm_fp = [&](const float* Xf, size_t woff, const float* bias, unsigned int* Cp,
                     int M, int N, int K, bool relu) {
    int nwg = (M >> 7) * (N >> 7);
    if (relu) k_gemm_u<0, 1, true ><<<nwg, 256, 0, stream>>>(Xf, nullptr, whi + woff, wlo + woff,
                                                             bias, nullptr, Cp, M, N, K);
    else      k_gemm_u<0, 1, false><<<nwg, 256, 0, stream>>>(Xf, nullptr, whi + woff, wlo + woff,
                                                             bias, nullptr, Cp, M, N, K);
  };
  auto gemm_pf = [&](const unsigned int* Xp, size_t woff, const float* bias, float* Cf,
                     int M, int N, int K) {
    int nwg = (M >> 7) * (N >> 7);
    k_gemm_u<1, 0, false><<<nwg, 256, 0, stream>>>(nullptr, Xp, whi + woff, wlo + woff,
                                                   bias, Cf, nullptr, M, N, K);
  };

  // FFN chunked at MCH_ rows so hidden chunk (122 MB) stays L3-resident
  auto ffn = [&](const float* srcf, int M, size_t w1, size_t w2) {
    int done = 0;
    while (done < M) {
      int mc = M - done; if (mc > MCH_) mc = MCH_;
      gemm_fp(srcf + (size_t)done * DM, w1, nullptr, hidp, mc, DFF, DM, true);
      gemm_pf(hidp, w2, nullptr, kbuf + (size_t)done * DM, mc, DM, DFF);
      done += mc;
    }
  };
  auto attn_self = [&](const float* srcf, int Lq, size_t wyu, const float* bout, int TK) {
    int M = B_ * Lq;
    int G8 = (Lq + 7) >> 3;
    gemm_fp(srcf, wyu, nullptr, yup, M, 512, DM, false);
    k_corr2<1, 0><<<B_, 256, 0, stream>>>(nullptr, yup, 512, srcf, nullptr, 256,
                                          wtop, dtop, Lq, Lq, TK);
    k_gather5<1><<<B_ * G8, 256, 0, stream>>>(yup + 256, 512, wtop, dtop, q, nullptr, bout,
                                              Lq, Lq, TK, G8);
  };
  auto attn_cross = [&](size_t wq2, size_t wkv, size_t wo2, const float* bq,
                        const float* bkv, const float* bo, int TK) {
    int G8 = (LD + 7) >> 3;
    gemm_fp(dec, wq2, bq, qxp, MD, DM, DM, false);
    gemm_fp(enc, wkv, bkv, yup, ME, 512, DM, false);
    k_corr2<1, 1><<<B_, 256, 0, stream>>>(nullptr, qxp, 256, nullptr, yup, 512,
                                          wtop, dtop, LD, LE, TK);
    k_gather5<0><<<B_ * G8, 256, 0, stream>>>(yup + 256, 512, wtop, dtop, nullptr, gthp, nullptr,
                                              LD, LE, TK, G8);
    gemm_pf(gthp, wo2, bo, q, MD, DM, DM);
  };

  // ---- preprocess + embeddings ----
  k_pre<<<B_, 128, 0, stream>>>(x, spad, trend);
  k_conv3<<<B_, 256, 0, stream>>>(x, we_enc, enc, LE);
  k_conv3<<<B_, 256, 0, stream>>>(spad, we_dec, dec, LD);

  // ---- encoder ----
  for (int i = 0; i < 2; ++i) {
    size_t e = enc_base(i);
    attn_self(enc, LE, e + 0, biasb + (size_t)i * 256, 13);
    k_decomp<0><<<4 * B_, 128, 0, stream>>>(enc, q, enc, nullptr, LE);
    ffn(enc, ME, e + 131072, e + 393216);
    k_decomp<0><<<4 * B_, 128, 0, stream>>>(enc, kbuf, enc, nullptr, LE);
  }
  k_lnorm<<<B_, 256, 0, stream>>>(enc, enc_g, enc, LE);

  // ---- decoder ----
  for (int i = 0; i < 2; ++i) {
    size_t d = dec_base(i);
    size_t b_ = (size_t)i * DM;
    const float* Wt_i = dWt + (size_t)i * 5 * DM * 3;
    attn_self(dec, LD, d + 0, biasb + (size_t)(2 + i) * 256, 14);
    k_decomp<1><<<4 * B_, 128, 0, stream>>>(dec, q, dec, kbuf, LD);
    k_trendconv<<<B_, 256, 0, stream>>>(kbuf, Wt_i, trend, LD);
    attn_cross(d + 131072, d + 196608, d + 327680, cbq + b_, biasb + 1024 + (size_t)i * 512, cbo + b_, 14);
    k_decomp<1><<<4 * B_, 128, 0, stream>>>(dec, q, dec, kbuf, LD);
    k_trendconv<<<B_, 256, 0, stream>>>(kbuf, Wt_i, trend, LD);
    ffn(dec, MD, d + 393216, d + 655360);
    k_decomp<1><<<4 * B_, 128, 0, stream>>>(dec, kbuf, dec, q, LD);
    k_trendconv<<<B_, 256, 0, stream>>>(q, Wt_i, trend, LD);
  }
  k_lnorm<<<B_, 256, 0, stream>>>(dec, dec_g, dec, LD);

  // ---- output head ----
  k_final<<<B_, 256, 0, stream>>>(dec, trend, projW, projb, bng, bnb, bnrm, bnrv, fcW, fcb, outp);
}

// Round 17
// 5736.509 us; speedup vs baseline: 1.0130x; 1.0130x over previous
//
#include <hip/hip_runtime.h>
#include <hip/hip_bf16.h>
#include <cstdint>
#include <cstddef>

// Autoformer forward, MI355X. Round 17: r15 config (unchunked FFN, best 5745us)
// + k_decomp widened to 256 threads / 4-way t-split (occupancy 10->20 waves/CU).
#define B_   1024
#define LE   96
#define LD   116
#define DM   256
#define DFF  1024

typedef __attribute__((ext_vector_type(8))) short bf16x8;
typedef __attribute__((ext_vector_type(4))) float f32x4;

static __device__ __forceinline__ unsigned short f2b(float f) {
  __hip_bfloat16 h = __float2bfloat16(f);
  return *reinterpret_cast<unsigned short*>(&h);
}
static __device__ __forceinline__ float asf(unsigned int u) { return __uint_as_float(u); }
static __device__ __forceinline__ void split1(float f, unsigned short& h, unsigned short& l) {
  h = f2b(f);
  l = f2b(f - asf((unsigned int)h << 16));
}
static __device__ __forceinline__ unsigned int pck(float f) {
  unsigned short h, l; split1(f, h, l);
  return ((unsigned int)h << 16) | l;
}
static __device__ __forceinline__ float unp(unsigned int p) {
  return asf(p & 0xFFFF0000u) + asf(p << 16);
}
static __device__ __forceinline__ void split8(float4 a, float4 b, uint4& h4, uint4& l4) {
  float f[8] = {a.x, a.y, a.z, a.w, b.x, b.y, b.z, b.w};
  unsigned int hp[4], lp[4];
#pragma unroll
  for (int j = 0; j < 4; ++j) {
    unsigned short h0, l0, h1, l1;
    split1(f[2 * j], h0, l0);
    split1(f[2 * j + 1], h1, l1);
    hp[j] = (unsigned int)h0 | ((unsigned int)h1 << 16);
    lp[j] = (unsigned int)l0 | ((unsigned int)l1 << 16);
  }
  h4 = make_uint4(hp[0], hp[1], hp[2], hp[3]);
  l4 = make_uint4(lp[0], lp[1], lp[2], lp[3]);
}
static __device__ __forceinline__ void unpack8(uint4 a, uint4 b, uint4& h, uint4& l) {
  h.x = (a.y & 0xFFFF0000u) | (a.x >> 16);
  l.x = (a.y << 16) | (a.x & 0xFFFFu);
  h.y = (a.w & 0xFFFF0000u) | (a.z >> 16);
  l.y = (a.w << 16) | (a.z & 0xFFFFu);
  h.z = (b.y & 0xFFFF0000u) | (b.x >> 16);
  l.z = (b.y << 16) | (b.x & 0xFFFFu);
  h.w = (b.w & 0xFFFF0000u) | (b.z >> 16);
  l.w = (b.w << 16) | (b.z & 0xFFFFu);
}

typedef const __attribute__((address_space(1))) void* gas_ptr;
typedef __attribute__((address_space(3))) void* las_ptr;
static __device__ __forceinline__ void gload16(const void* g, void* l) {
  __builtin_amdgcn_global_load_lds((gas_ptr)g, (las_ptr)l, 16, 0, 0);
}

// ---------------- workspace ----------------
#define NE_ ((size_t)B_ * LE * DM)
#define ND_ ((size_t)B_ * LD * DM)
#define NS_ ((size_t)B_ * LD * 5)
#define NW_ ((size_t)B_ * 16)
#define WBF_ 3145728

static constexpr size_t o_enc   = 0;
static constexpr size_t o_dec   = o_enc   + NE_ * 4;
static constexpr size_t o_q     = o_dec   + ND_ * 4;
static constexpr size_t o_kbuf  = o_q     + ND_ * 4;
static constexpr size_t o_yup   = o_kbuf  + ND_ * 4;   // packed [M][512]
static constexpr size_t o_qxp   = o_yup   + ND_ * 8;   // packed cross-Q [MD][256]
static constexpr size_t o_gthp  = o_qxp   + ND_ * 4;   // packed cross gather out
static constexpr size_t o_hidp  = o_gthp  + ND_ * 4;   // packed FFN hidden [M][1024]
static constexpr size_t o_spad  = o_hidp  + ND_ * 16;
static constexpr size_t o_trend = o_spad  + NS_ * 4;
static constexpr size_t o_wtop  = o_trend + NS_ * 4;
static constexpr size_t o_dtop  = o_wtop  + NW_ * 4;
static constexpr size_t o_bias  = o_dtop  + NW_ * 4;   // 2048 floats
static constexpr size_t o_whi   = o_bias  + 2048 * 4;
static constexpr size_t o_wlo   = o_whi   + (size_t)WBF_ * 2;
static constexpr size_t WS_TOTAL = o_wlo  + (size_t)WBF_ * 2;

__device__ __align__(256) unsigned char g_ws[WS_TOTAL];

static __host__ __device__ constexpr size_t enc_base(int i) { return (size_t)i * 655360; }
static __host__ __device__ constexpr size_t dec_base(int i) { return 1310720 + (size_t)i * 917504; }

// ---------------- weight split cast ----------------
__global__ __launch_bounds__(256)
void k_cast_split(const float* __restrict__ in, unsigned short* __restrict__ hi,
                  unsigned short* __restrict__ lo, int n) {
  int i = (blockIdx.x * 256 + threadIdx.x) * 4;
  if (i < n) {
    float4 v = *(const float4*)(in + i);
    unsigned int hp[2], lp[2];
    float f[4] = {v.x, v.y, v.z, v.w};
#pragma unroll
    for (int j = 0; j < 2; ++j) {
      unsigned short h0, l0, h1, l1;
      split1(f[2 * j], h0, l0);
      split1(f[2 * j + 1], h1, l1);
      hp[j] = (unsigned int)h0 | ((unsigned int)h1 << 16);
      lp[j] = (unsigned int)l0 | ((unsigned int)l1 << 16);
    }
    *(uint2*)(hi + i) = make_uint2(hp[0], hp[1]);
    *(uint2*)(lo + i) = make_uint2(lp[0], lp[1]);
  }
}

// ---------------- weight composition ----------------
__global__ __launch_bounds__(256)
void k_compose_qk(const float* __restrict__ Wq, const float* __restrict__ Wk,
                  unsigned short* __restrict__ hi, unsigned short* __restrict__ lo) {
  int j = blockIdx.x, i = threadIdx.x;
  __shared__ float wkc[256];
  wkc[i] = Wk[i * 256 + j];
  __syncthreads();
  float s = 0.f;
  for (int o = 0; o < 256; ++o) s += Wq[o * 256 + i] * wkc[o];
  unsigned short h, l; split1(s, h, l);
  hi[j * 256 + i] = h; lo[j * 256 + i] = l;
}
__global__ __launch_bounds__(256)
void k_compose_vo(const float* __restrict__ Wv, const float* __restrict__ Wo,
                  unsigned short* __restrict__ hi, unsigned short* __restrict__ lo) {
  int o2 = blockIdx.x, i = threadIdx.x;
  __shared__ float woc[256];
  woc[i] = Wo[o2 * 256 + i];
  __syncthreads();
  float s = 0.f;
  for (int c = 0; c < 256; ++c) s += woc[c] * Wv[c * 256 + i];
  unsigned short h, l; split1(s, h, l);
  hi[o2 * 256 + i] = h; lo[o2 * 256 + i] = l;
}
__global__ __launch_bounds__(256)
void k_bout(const float* __restrict__ Wo, const float* __restrict__ bv,
            const float* __restrict__ bo, float* __restrict__ dst) {
  int o2 = threadIdx.x;
  __shared__ float bvs[256];
  bvs[o2] = bv[o2];
  __syncthreads();
  float s = bo[o2];
  for (int c = 0; c < 256; ++c) s += Wo[o2 * 256 + c] * bvs[c];
  dst[o2] = s;
}
__global__ __launch_bounds__(256)
void k_cat2(const float* __restrict__ a, const float* __restrict__ b, float* __restrict__ dst) {
  int t = threadIdx.x;
  dst[t] = a[t];
  dst[256 + t] = b[t];
}

// ---------------- preprocess ----------------
__global__ __launch_bounds__(128)
void k_pre(const float* __restrict__ x, float* __restrict__ spad, float* __restrict__ trend) {
  int b = blockIdx.x;
  __shared__ float xs[LE * 5];
  __shared__ float mx[5];
  const float* xb = x + (size_t)b * LE * 5;
  for (int i = threadIdx.x; i < LE * 5; i += 128) xs[i] = xb[i];
  __syncthreads();
  if (threadIdx.x < 5) {
    float s = 0.f;
    for (int t = 0; t < LE; ++t) s += xs[t * 5 + threadIdx.x];
    mx[threadIdx.x] = s * (1.f / 96.f);
  }
  __syncthreads();
  float* spb = spad + (size_t)b * LD * 5;
  float* trb = trend + (size_t)b * LD * 5;
  for (int i = threadIdx.x; i < LE * 5; i += 128) {
    int t = i / 5, c = i % 5;
    float s = 0.f;
    for (int d = -12; d <= 12; ++d) {
      int tt = t + d; tt = tt < 0 ? 0 : (tt > LE - 1 ? LE - 1 : tt);
      s += xs[tt * 5 + c];
    }
    float m = s * (1.f / 25.f);
    trb[t * 5 + c] = m;
    spb[(t + 20) * 5 + c] = xs[i] - m;
  }
  for (int i = threadIdx.x; i < 20 * 5; i += 128) {
    int t = i / 5, c = i % 5;
    spb[t * 5 + c] = 0.f;
    trb[(LE + t) * 5 + c] = mx[c];
  }
}

// ---------------- circular 3-tap conv (f32 out) ----------------
__global__ __launch_bounds__(256)
void k_conv3(const float* __restrict__ xin, const float* __restrict__ W,
             float* __restrict__ out, int L) {
  int b = blockIdx.x, o = threadIdx.x;
  __shared__ float xs[LD * 5];
  const float* xb = xin + (size_t)b * L * 5;
  for (int i = o; i < L * 5; i += 256) xs[i] = xb[i];
  __syncthreads();
  float w[15];
#pragma unroll
  for (int j = 0; j < 15; ++j) w[j] = W[o * 15 + j];
  size_t ob = (size_t)b * L * DM + o;
  for (int l = 0; l < L; ++l) {
    int lm = (l == 0) ? L - 1 : l - 1;
    int lp = (l == L - 1) ? 0 : l + 1;
    float acc = 0.f;
#pragma unroll
    for (int c = 0; c < 5; ++c)
      acc += xs[lm * 5 + c] * w[c * 3] + xs[l * 5 + c] * w[c * 3 + 1] + xs[lp * 5 + c] * w[c * 3 + 2];
    out[ob + (size_t)l * DM] = acc;
  }
}

// ---------------- unified MFMA GEMM, double-buffered 2-phase K-loop ----------------
template <int XMODE, int OMODE, bool RELU>
__global__ __launch_bounds__(256)
void k_gemm_u(const float* __restrict__ Xf, const unsigned int* __restrict__ Xp,
              const unsigned short* __restrict__ Whi, const unsigned short* __restrict__ Wlo,
              const float* __restrict__ bias, float* __restrict__ Cf,
              unsigned int* __restrict__ Cp, int M, int N, int K) {
  __shared__ __align__(16) unsigned short Xh[2][4096], Xl[2][4096], Wh[2][4096], Wl[2][4096];
  const int nwg = gridDim.x, bid = blockIdx.x;
  const int wg = (bid & 7) * (nwg >> 3) + (bid >> 3);   // XCD swizzle (nwg%8==0)
  const int NT = N >> 7;
  const int mt = wg / NT, nt = wg % NT;
  const int m0 = mt << 7, n0 = nt << 7;
  const int tid = threadIdx.x, lane = tid & 63, wv = tid >> 6;
  const int wm = (wv >> 1) << 6, wn = (wv & 1) << 6;

  f32x4 acc[4][4];
#pragma unroll
  for (int i = 0; i < 4; ++i)
#pragma unroll
    for (int j = 0; j < 4; ++j) acc[i][j] = (f32x4){0.f, 0.f, 0.f, 0.f};

  const int r0 = tid >> 2,        ls0 = (tid & 3) ^ ((r0 >> 1) & 3);
  const int r1 = 64 + (tid >> 2), ls1 = (tid & 3) ^ ((r1 >> 1) & 3);
  const unsigned short* wh0 = Whi + (size_t)(n0 + r0) * K + (ls0 << 3);
  const unsigned short* wh1 = Whi + (size_t)(n0 + r1) * K + (ls1 << 3);
  const unsigned short* wl0 = Wlo + (size_t)(n0 + r0) * K + (ls0 << 3);
  const unsigned short* wl1 = Wlo + (size_t)(n0 + r1) * K + (ls1 << 3);
  const int lofs0 = (tid & ~63) << 3, lofs1 = 2048 + ((tid & ~63) << 3);

  const int xrow0 = tid >> 2, xpart = tid & 3;
  const int xrow1 = 64 + xrow0;
  const int xph0 = xpart ^ ((xrow0 >> 1) & 3);
  const int xph1 = xpart ^ ((xrow1 >> 1) & 3);
  const int xo0 = xrow0 * 32 + (xph0 << 3);
  const int xo1 = xrow1 * 32 + (xph1 << 3);
  const float* xf0 = Xf + (size_t)(m0 + xrow0) * K + (xpart << 3);
  const float* xf1 = Xf + (size_t)(m0 + xrow1) * K + (xpart << 3);
  const unsigned int* xp0 = Xp + (size_t)(m0 + xrow0) * K + (xpart << 3);
  const unsigned int* xp1 = Xp + (size_t)(m0 + xrow1) * K + (xpart << 3);

  const int nsteps = K >> 5;

  auto stage = [&](int bsel, int k0) {
    gload16(wh0 + k0, &Wh[bsel][lofs0]);
    gload16(wh1 + k0, &Wh[bsel][lofs1]);
    gload16(wl0 + k0, &Wl[bsel][lofs0]);
    gload16(wl1 + k0, &Wl[bsel][lofs1]);
    uint4 h, l;
    if (XMODE == 0) {
      float4 a0 = *(const float4*)(xf0 + k0);
      float4 b0 = *(const float4*)(xf0 + k0 + 4);
      float4 a1 = *(const float4*)(xf1 + k0);
      float4 b1 = *(const float4*)(xf1 + k0 + 4);
      split8(a0, b0, h, l);
      *(uint4*)&Xh[bsel][xo0] = h; *(uint4*)&Xl[bsel][xo0] = l;
      split8(a1, b1, h, l);
      *(uint4*)&Xh[bsel][xo1] = h; *(uint4*)&Xl[bsel][xo1] = l;
    } else {
      uint4 a0 = *(const uint4*)(xp0 + k0);
      uint4 b0 = *(const uint4*)(xp0 + k0 + 4);
      uint4 a1 = *(const uint4*)(xp1 + k0);
      uint4 b1 = *(const uint4*)(xp1 + k0 + 4);
      unpack8(a0, b0, h, l);
      *(uint4*)&Xh[bsel][xo0] = h; *(uint4*)&Xl[bsel][xo0] = l;
      unpack8(a1, b1, h, l);
      *(uint4*)&Xh[bsel][xo1] = h; *(uint4*)&Xl[bsel][xo1] = l;
    }
  };

  stage(0, 0);
  __syncthreads();

  for (int step = 0; step < nsteps; ++step) {
    int cur = step & 1;
    if (step + 1 < nsteps) stage(cur ^ 1, (step + 1) << 5);
    bf16x8 ah[4], al[4], bh[4], bl[4];
#pragma unroll
    for (int i = 0; i < 4; ++i) {
      int ra = wm + i * 16 + (lane & 15);
      int sa = (lane >> 4) ^ ((ra >> 1) & 3);
      ah[i] = *(const bf16x8*)(&Xh[cur][ra * 32 + (sa << 3)]);
      al[i] = *(const bf16x8*)(&Xl[cur][ra * 32 + (sa << 3)]);
      int rb = wn + i * 16 + (lane & 15);
      int sb = (lane >> 4) ^ ((rb >> 1) & 3);
      bh[i] = *(const bf16x8*)(&Wh[cur][rb * 32 + (sb << 3)]);
      bl[i] = *(const bf16x8*)(&Wl[cur][rb * 32 + (sb << 3)]);
    }
#pragma unroll
    for (int i = 0; i < 4; ++i)
#pragma unroll
      for (int j = 0; j < 4; ++j) {
        acc[i][j] = __builtin_amdgcn_mfma_f32_16x16x32_bf16(ah[i], bh[j], acc[i][j], 0, 0, 0);
        acc[i][j] = __builtin_amdgcn_mfma_f32_16x16x32_bf16(al[i], bh[j], acc[i][j], 0, 0, 0);
        acc[i][j] = __builtin_amdgcn_mfma_f32_16x16x32_bf16(ah[i], bl[j], acc[i][j], 0, 0, 0);
      }
    __syncthreads();
  }

  const int col_base = n0 + wn + (lane & 15);
  const int row_base = m0 + wm + ((lane >> 4) << 2);
#pragma unroll
  for (int j = 0; j < 4; ++j) {
    int col = col_base + j * 16;
    float bv = bias ? bias[col] : 0.f;
#pragma unroll
    for (int i = 0; i < 4; ++i) {
      int rb2 = row_base + i * 16;
#pragma unroll
      for (int q = 0; q < 4; ++q) {
        float o = acc[i][j][q] + bv;
        if (RELU) o = fmaxf(o, 0.f);
        size_t idx = (size_t)(rb2 + q) * N + col;
        if (OMODE == 0) Cf[idx] = o;
        else            Cp[idx] = pck(o);
      }
    }
  }
}

// ---------------- corr (MFMA Gram, per-side f32/packed) + fused top-k/softmax ----------------
template <int QM, int KM>
__global__ __launch_bounds__(256)
void k_corr2(const float* __restrict__ Qf, const unsigned int* __restrict__ Qp, int sq,
             const float* __restrict__ Kf, const unsigned int* __restrict__ Kpk, int sk,
             float* __restrict__ wout, int* __restrict__ dout,
             int L, int S, int TK) {
  __shared__ __align__(16) unsigned char smem[65536];
  unsigned short* qh = (unsigned short*)smem;   // [128][64]
  unsigned short* ql = qh + 8192;
  unsigned short* kh = ql + 8192;
  unsigned short* kl = kh + 8192;
  float* G = (float*)smem;                      // [128][128] overlays after K-loop
  int b = blockIdx.x, tid = threadIdx.x, lane = tid & 63, wv = tid >> 6;
  int wm = (wv >> 1) << 6, wn = (wv & 1) << 6;
  const float*        Qfb = Qf  + (size_t)b * L * sq;
  const unsigned int* Qpb = Qp  + (size_t)b * L * sq;
  const float*        Kfb = Kf  + (size_t)b * S * sk;
  const unsigned int* Kpb = Kpk + (size_t)b * S * sk;
  f32x4 acc[4][4];
#pragma unroll
  for (int i = 0; i < 4; ++i)
#pragma unroll
    for (int j = 0; j < 4; ++j) acc[i][j] = (f32x4){0.f, 0.f, 0.f, 0.f};

  for (int c0 = 0; c0 < DM; c0 += 64) {
#pragma unroll
    for (int u = 0; u < 4; ++u) {
      int seg = (u << 8) + tid;
      int row = seg >> 3, ps = seg & 7;
      int phys = ps ^ (row & 7);
      uint4 h = make_uint4(0u, 0u, 0u, 0u), l = make_uint4(0u, 0u, 0u, 0u);
      if (row < L) {
        if (QM == 0) {
          float4 a = *(const float4*)(Qfb + (size_t)row * sq + c0 + (ps << 3));
          float4 c = *(const float4*)(Qfb + (size_t)row * sq + c0 + (ps << 3) + 4);
          split8(a, c, h, l);
        } else {
          uint4 a = *(const uint4*)(Qpb + (size_t)row * sq + c0 + (ps << 3));
          uint4 c = *(const uint4*)(Qpb + (size_t)row * sq + c0 + (ps << 3) + 4);
          unpack8(a, c, h, l);
        }
      }
      *(uint4*)(qh + row * 64 + (phys << 3)) = h;
      *(uint4*)(ql + row * 64 + (phys << 3)) = l;
      h = make_uint4(0u, 0u, 0u, 0u); l = make_uint4(0u, 0u, 0u, 0u);
      if (row < S) {
        if (KM == 0) {
          float4 a = *(const float4*)(Kfb + (size_t)row * sk + c0 + (ps << 3));
          float4 c = *(const float4*)(Kfb + (size_t)row * sk + c0 + (ps << 3) + 4);
          split8(a, c, h, l);
        } else {
          uint4 a = *(const uint4*)(Kpb + (size_t)row * sk + c0 + (ps << 3));
          uint4 c = *(const uint4*)(Kpb + (size_t)row * sk + c0 + (ps << 3) + 4);
          unpack8(a, c, h, l);
        }
      }
      *(uint4*)(kh + row * 64 + (phys << 3)) = h;
      *(uint4*)(kl + row * 64 + (phys << 3)) = l;
    }
    __syncthreads();
#pragma unroll
    for (int ks = 0; ks < 2; ++ks) {
      bf16x8 aqh[4], aql[4], bkh[4], bkl[4];
#pragma unroll
      for (int i = 0; i < 4; ++i) {
        int ra = wm + i * 16 + (lane & 15);
        int sa = ((ks << 2) + (lane >> 4)) ^ (ra & 7);
        aqh[i] = *(const bf16x8*)(qh + ra * 64 + (sa << 3));
        aql[i] = *(const bf16x8*)(ql + ra * 64 + (sa << 3));
        int rb = wn + i * 16 + (lane & 15);
        int sb = ((ks << 2) + (lane >> 4)) ^ (rb & 7);
        bkh[i] = *(const bf16x8*)(kh + rb * 64 + (sb << 3));
        bkl[i] = *(const bf16x8*)(kl + rb * 64 + (sb << 3));
      }
#pragma unroll
      for (int i = 0; i < 4; ++i)
#pragma unroll
        for (int j = 0; j < 4; ++j) {
          acc[i][j] = __builtin_amdgcn_mfma_f32_16x16x32_bf16(aqh[i], bkh[j], acc[i][j], 0, 0, 0);
          acc[i][j] = __builtin_amdgcn_mfma_f32_16x16x32_bf16(aql[i], bkh[j], acc[i][j], 0, 0, 0);
          acc[i][j] = __builtin_amdgcn_mfma_f32_16x16x32_bf16(aqh[i], bkl[j], acc[i][j], 0, 0, 0);
        }
    }
    __syncthreads();
  }
#pragma unroll
  for (int i = 0; i < 4; ++i)
#pragma unroll
    for (int j = 0; j < 4; ++j)
#pragma unroll
      for (int q = 0; q < 4; ++q)
        G[(wm + i * 16 + ((lane >> 4) << 2) + q) * 128 + wn + j * 16 + (lane & 15)] = acc[i][j][q];
  __syncthreads();
  float s = 0.f;
  if (tid < L) {
    for (int t = 0; t < L; ++t) {
      int r = t - tid; if (r < 0) r += L;
      s += G[t * 128 + r];
    }
    s *= (1.f / 256.f);
  }
  __syncthreads();

  float* vals = (float*)smem;
  float* rv   = vals + 128;
  int*   ri   = (int*)(rv + 128);
  float* selv = (float*)(ri + 128);
  int*   seli = (int*)(selv + 16);
  if (tid < 128) vals[tid] = (tid < L) ? s : -3e38f;
  __syncthreads();
  for (int it = 0; it < TK; ++it) {
    if (tid < 128) { rv[tid] = vals[tid]; ri[tid] = tid; }
    __syncthreads();
    for (int off = 64; off >= 1; off >>= 1) {
      if (tid < off) {
        float v2 = rv[tid + off]; int i2 = ri[tid + off];
        if (v2 > rv[tid] || (v2 == rv[tid] && i2 < ri[tid])) { rv[tid] = v2; ri[tid] = i2; }
      }
      __syncthreads();
    }
    if (tid == 0) { selv[it] = rv[0]; seli[it] = ri[0]; vals[ri[0]] = -3e38f; }
    __syncthreads();
  }
  if (tid == 0) {
    float mxv = selv[0];
    float e[16]; float sum = 0.f;
    for (int j = 0; j < TK; ++j) { e[j] = expf(selv[j] - mxv); sum += e[j]; }
    float inv = 1.f / sum;
    for (int j = 0; j < TK; ++j) {
      wout[(size_t)b * 16 + j] = e[j] * inv;
      dout[(size_t)b * 16 + j] = seli[j];
    }
  }
}

// ---------------- gather: 8 l/block, packed V in, XCD-affine ----------------
template <int SELF>
__global__ __launch_bounds__(256)
void k_gather5(const unsigned int* __restrict__ V, int sv, const float* __restrict__ wtop,
               const int* __restrict__ dtop, float* __restrict__ outf,
               unsigned int* __restrict__ outp, const float* __restrict__ bout,
               int L, int S, int TK, int G8) {
  int p = blockIdx.x;
  int xcd = p & 7, q8 = p >> 3;
  int lg = q8 % G8;
  int b = ((q8 / G8) << 3) + xcd;
  __shared__ float wsm[16];
  __shared__ int   dsm[16];
  __shared__ float bsm[256];
  if (threadIdx.x < TK) {
    wsm[threadIdx.x] = wtop[(size_t)b * 16 + threadIdx.x];
    dsm[threadIdx.x] = dtop[(size_t)b * 16 + threadIdx.x];
  }
  if (SELF) bsm[threadIdx.x] = bout[threadIdx.x];
  __syncthreads();
  int wv = threadIdx.x >> 6, lane = threadIdx.x & 63;
  int c4 = lane << 2;
  const unsigned int* Vb = V + (size_t)b * S * sv + c4;
  size_t ob = (size_t)b * L * DM + c4;
#pragma unroll
  for (int u = 0; u < 2; ++u) {
    int l = (lg << 3) + (wv << 1) + u;
    if (l < L) {
      float a0 = 0.f, a1 = 0.f, a2 = 0.f, a3 = 0.f;
      for (int j = 0; j < TK; ++j) {
        int r = l + dsm[j]; if (r >= L) r -= L;
        if (r < S) {
          uint4 v = *(const uint4*)(Vb + (size_t)r * sv);
          float w = wsm[j];
          a0 += w * unp(v.x); a1 += w * unp(v.y); a2 += w * unp(v.z); a3 += w * unp(v.w);
        }
      }
      if (SELF) {
        float4 o;
        o.x = a0 + bsm[c4];     o.y = a1 + bsm[c4 + 1];
        o.z = a2 + bsm[c4 + 2]; o.w = a3 + bsm[c4 + 3];
        *(float4*)(outf + ob + (size_t)l * DM) = o;
      } else {
        uint4 o; o.x = pck(a0); o.y = pck(a1); o.z = pck(a2); o.w = pck(a3);
        *(uint4*)(outp + ob + (size_t)l * DM) = o;
      }
    }
  }
}

// ---------------- series_decomp: 256 thr, 4-way t-split, f32 only ----------------
template <int MOUT>
__global__ __launch_bounds__(256)
void k_decomp(const float* __restrict__ X, const float* __restrict__ Y,
              float* __restrict__ out, float* __restrict__ mout, int L) {
  int b = blockIdx.x >> 2, qd = blockIdx.x & 3;
  __shared__ float tmp[LD * 64];
  size_t base = (size_t)b * L * DM + qd * 64;
  for (int i = threadIdx.x; i < L * 64; i += 256) {
    int t = i >> 6, cc = i & 63;
    size_t gi = base + (size_t)t * DM + cc;
    tmp[i] = X[gi] + Y[gi];
  }
  __syncthreads();
  int c = threadIdx.x & 63, th = threadIdx.x >> 6;   // th in 0..3
  int quarter = (L + 3) >> 2;
  int t0 = th * quarter;
  int t1 = t0 + quarter; if (t1 > L) t1 = L;
  if (t0 >= L) return;
  float s = 0.f;
  for (int d = -12; d <= 12; ++d) {
    int t2 = t0 + d; t2 = t2 < 0 ? 0 : (t2 > L - 1 ? L - 1 : t2);
    s += tmp[t2 * 64 + c];
  }
  for (int t = t0; t < t1; ++t) {
    float m = s * (1.f / 25.f);
    size_t gi = base + (size_t)t * DM + c;
    out[gi] = tmp[t * 64 + c] - m;
    if (MOUT) mout[gi] = m;
    int ai = t + 13; if (ai > L - 1) ai = L - 1;
    int si = t - 12; if (si < 0) si = 0;
    s += tmp[ai * 64 + c] - tmp[si * 64 + c];
  }
}

// ---------------- my_layernorm (f32 only) ----------------
__global__ __launch_bounds__(256)
void k_lnorm(const float* __restrict__ X, const float* __restrict__ g,
             float* __restrict__ out, int L) {
  int b = blockIdx.x;
  __shared__ float mu_s[LD], inv_s[LD];
  size_t base = (size_t)b * L * DM;
  int wv = threadIdx.x >> 6, lane = threadIdx.x & 63;
  for (int t = wv; t < L; t += 4) {
    float s = 0.f, s2 = 0.f;
#pragma unroll
    for (int qd = 0; qd < 4; ++qd) {
      float val = X[base + (size_t)t * DM + lane + 64 * qd];
      s += val; s2 += val * val;
    }
    for (int off = 32; off; off >>= 1) { s += __shfl_xor(s, off); s2 += __shfl_xor(s2, off); }
    if (lane == 0) {
      float mu = s * (1.f / 256.f);
      mu_s[t] = mu;
      inv_s[t] = rsqrtf(s2 * (1.f / 256.f) - mu * mu + 1e-5f);
    }
  }
  __syncthreads();
  int c = threadIdx.x;
  float gc = g[c];
  float sm = 0.f;
  for (int t = 0; t < L; ++t) sm += (X[base + (size_t)t * DM + c] - mu_s[t]) * inv_s[t];
  float mn = sm / (float)L;
  for (int t = 0; t < L; ++t) {
    float xn = (X[base + (size_t)t * DM + c] - mu_s[t]) * inv_s[t];
    out[base + (size_t)t * DM + c] = gc * (xn - mn);
  }
}

// ---------------- trend conv: rolling single-read, 1 block/batch ----------------
__global__ __launch_bounds__(256)
void k_trendconv(const float* __restrict__ T, const float* __restrict__ Wt,
                 float* __restrict__ trend, int L) {
  int b = blockIdx.x;
  int tid = threadIdx.x, wv = tid >> 6, lane = tid & 63;
  int c0 = lane << 2;
  float w[5][3][4];
#pragma unroll
  for (int o = 0; o < 5; ++o)
#pragma unroll
    for (int k = 0; k < 4; ++k) {
      w[o][0][k] = Wt[o * 768 + (c0 + k) * 3 + 0];
      w[o][1][k] = Wt[o * 768 + (c0 + k) * 3 + 1];
      w[o][2][k] = Wt[o * 768 + (c0 + k) * 3 + 2];
    }
  size_t base = (size_t)b * L * DM;
  int chunk = (L + 3) >> 2;
  int l0 = wv * chunk;
  int cnt = (L - l0 < chunk) ? (L - l0) : chunk;
  if (cnt <= 0) return;
  int lmi = (l0 == 0) ? L - 1 : l0 - 1;
  float4 pm = *(const float4*)(T + base + (size_t)lmi * DM + c0);
  float4 p0 = *(const float4*)(T + base + (size_t)l0  * DM + c0);
  for (int i = 0; i < cnt; ++i) {
    int l = l0 + i;
    int lp = (l == L - 1) ? 0 : l + 1;
    float4 pp = *(const float4*)(T + base + (size_t)lp * DM + c0);
    float fm[4] = {pm.x, pm.y, pm.z, pm.w};
    float f0[4] = {p0.x, p0.y, p0.z, p0.w};
    float fp[4] = {pp.x, pp.y, pp.z, pp.w};
    float acc[5];
#pragma unroll
    for (int o = 0; o < 5; ++o) {
      float a = 0.f;
#pragma unroll
      for (int k = 0; k < 4; ++k)
        a += fm[k] * w[o][0][k] + f0[k] * w[o][1][k] + fp[k] * w[o][2][k];
      acc[o] = a;
    }
#pragma unroll
    for (int off = 32; off; off >>= 1)
#pragma unroll
      for (int o = 0; o < 5; ++o) acc[o] += __shfl_xor(acc[o], off);
    if (lane == 0) {
#pragma unroll
      for (int o = 0; o < 5; ++o)
        trend[((size_t)b * L + l) * 5 + o] += acc[o];
    }
    pm = p0; p0 = pp;
  }
}

// ---------------- final head ----------------
__global__ __launch_bounds__(256)
void k_final(const float* __restrict__ dec, const float* __restrict__ trend,
             const float* __restrict__ projW, const float* __restrict__ projb,
             const float* __restrict__ bng, const float* __restrict__ bnb,
             const float* __restrict__ bnrm, const float* __restrict__ bnrv,
             const float* __restrict__ fcW, const float* __restrict__ fcb,
             float* __restrict__ outp) {
  int b = blockIdx.x, c = threadIdx.x;
  __shared__ float red[5][256];
  float xv = dec[((size_t)b * LD + (LD - 1)) * DM + c];
#pragma unroll
  for (int o = 0; o < 5; ++o) red[o][c] = xv * projW[o * 256 + c];
  __syncthreads();
  for (int off = 128; off >= 1; off >>= 1) {
    if (c < off) {
#pragma unroll
      for (int o = 0; o < 5; ++o) red[o][c] += red[o][c + off];
    }
    __syncthreads();
  }
  if (c == 0) {
    float acc = fcb[0];
    for (int j = 0; j < 20; ++j) {
      int m5 = j % 5;
      float last = trend[((size_t)b * LD + (LD - 1)) * 5 + m5] + red[m5][0] + projb[m5];
      float h = (last - bnrm[j]) * rsqrtf(bnrv[j] + 1e-5f) * bng[j] + bnb[j];
      acc += h * fcW[j];
    }
    outp[b] = acc;
  }
}

// ================================ host ================================
extern "C" void kernel_launch(void* const* d_in, const int* in_sizes, int n_in,
                              void* d_out, int out_size, void* d_ws, size_t ws_size,
                              hipStream_t stream) {
  const float* x      = (const float*)d_in[0];
  const float* we_enc = (const float*)d_in[1];
  const float* we_dec = (const float*)d_in[2];
  const float* enc_Wq = (const float*)d_in[3];
  const float* enc_bq = (const float*)d_in[4];
  const float* enc_Wk = (const float*)d_in[5];
  const float* enc_bk = (const float*)d_in[6];
  const float* enc_Wv = (const float*)d_in[7];
  const float* enc_bv = (const float*)d_in[8];
  const float* enc_Wo = (const float*)d_in[9];
  const float* enc_bo = (const float*)d_in[10];
  const float* enc_W1 = (const float*)d_in[11];
  const float* enc_W2 = (const float*)d_in[12];
  const float* enc_g  = (const float*)d_in[13];
  const float* sWq = (const float*)d_in[15]; const float* sbq = (const float*)d_in[16];
  const float* sWk = (const float*)d_in[17]; const float* sbk = (const float*)d_in[18];
  const float* sWv = (const float*)d_in[19]; const float* sbv = (const float*)d_in[20];
  const float* sWo = (const float*)d_in[21]; const float* sbo = (const float*)d_in[22];
  const float* cWq = (const float*)d_in[23]; const float* cbq = (const float*)d_in[24];
  const float* cWk = (const float*)d_in[25]; const float* cbk = (const float*)d_in[26];
  const float* cWv = (const float*)d_in[27]; const float* cbv = (const float*)d_in[28];
  const float* cWo = (const float*)d_in[29]; const float* cbo = (const float*)d_in[30];
  const float* dW1 = (const float*)d_in[31]; const float* dW2 = (const float*)d_in[32];
  const float* dWt = (const float*)d_in[33];
  const float* dec_g  = (const float*)d_in[34];
  const float* projW = (const float*)d_in[36]; const float* projb = (const float*)d_in[37];
  const float* bng = (const float*)d_in[38]; const float* bnb = (const float*)d_in[39];
  const float* bnrm = (const float*)d_in[40]; const float* bnrv = (const float*)d_in[41];
  const float* fcW = (const float*)d_in[42]; const float* fcb = (const float*)d_in[43];
  (void)in_sizes; (void)n_in; (void)out_size; (void)d_ws; (void)ws_size;
  float* outp = (float*)d_out;

  void* symaddr = nullptr;
  if (hipGetSymbolAddress(&symaddr, HIP_SYMBOL(g_ws)) != hipSuccess || !symaddr) return;
  unsigned char* base = (unsigned char*)symaddr;
  float* enc   = (float*)(base + o_enc);
  float* dec   = (float*)(base + o_dec);
  float* q     = (float*)(base + o_q);
  float* kbuf  = (float*)(base + o_kbuf);
  unsigned int* yup  = (unsigned int*)(base + o_yup);
  unsigned int* qxp  = (unsigned int*)(base + o_qxp);
  unsigned int* gthp = (unsigned int*)(base + o_gthp);
  unsigned int* hidp = (unsigned int*)(base + o_hidp);
  float* spad  = (float*)(base + o_spad);
  float* trend = (float*)(base + o_trend);
  float* wtop  = (float*)(base + o_wtop);
  int*   dtop  = (int*)(base + o_dtop);
  float* biasb = (float*)(base + o_bias);
  unsigned short* whi = (unsigned short*)(base + o_whi);
  unsigned short* wlo = (unsigned short*)(base + o_wlo);

  const int ME = B_ * LE;
  const int MD = B_ * LD;

  auto cast = [&](const float* s, size_t off, int n) {
    k_cast_split<<<n / 1024, 256, 0, stream>>>(s, whi + off, wlo + off, n);
  };
  for (int i = 0; i < 2; ++i) {
    size_t e = enc_base(i), d = dec_base(i);
    size_t wq = (size_t)i * 65536, wf = (size_t)i * 262144;
    size_t b_ = (size_t)i * DM;
    k_compose_qk<<<256, 256, 0, stream>>>(enc_Wq + wq, enc_Wk + wq, whi + e, wlo + e);
    k_compose_vo<<<256, 256, 0, stream>>>(enc_Wv + wq, enc_Wo + wq, whi + e + 65536, wlo + e + 65536);
    k_bout<<<1, 256, 0, stream>>>(enc_Wo + wq, enc_bv + b_, enc_bo + b_, biasb + (size_t)i * 256);
    cast(enc_W1 + wf, e + 131072, 262144);
    cast(enc_W2 + wf, e + 393216, 262144);
    k_compose_qk<<<256, 256, 0, stream>>>(sWq + wq, sWk + wq, whi + d, wlo + d);
    k_compose_vo<<<256, 256, 0, stream>>>(sWv + wq, sWo + wq, whi + d + 65536, wlo + d + 65536);
    k_bout<<<1, 256, 0, stream>>>(sWo + wq, sbv + b_, sbo + b_, biasb + (size_t)(2 + i) * 256);
    cast(cWq + wq, d + 131072, 65536);
    cast(cWk + wq, d + 196608, 65536);
    cast(cWv + wq, d + 262144, 65536);
    cast(cWo + wq, d + 327680, 65536);
    cast(dW1 + wf, d + 393216, 262144);
    cast(dW2 + wf, d + 655360, 262144);
    k_cat2<<<1, 256, 0, stream>>>(cbk + b_, cbv + b_, biasb + 1024 + (size_t)i * 512);
  }

  auto gemm_fp = [&](const float* Xf, size_t woff, const float* bias, unsigned int* Cp,
                     int M, int N, int K, bool relu) {
    int nwg = (M >> 7) * (N >> 7);
    if (relu) k_gemm_u<0, 1, true ><<<nwg, 256, 0, stream>>>(Xf, nullptr, whi + woff, wlo + woff,
                                                             bias, nullptr, Cp, M, N, K);
    else      k_gemm_u<0, 1, false><<<nwg, 256, 0, stream>>>(Xf, nullptr, whi + woff, wlo + woff,
                                                             bias, nullptr, Cp, M, N, K);
  };
  auto gemm_pf = [&](const unsigned int* Xp, size_t woff, const float* bias, float* Cf,
                     int M, int N, int K) {
    int nwg = (M >> 7) * (N >> 7);
    k_gemm_u<1, 0, false><<<nwg, 256, 0, stream>>>(nullptr, Xp, whi + woff, wlo + woff,
                                                   bias, Cf, nullptr, M, N, K);
  };

  auto ffn = [&](const float* srcf, int M, size_t w1, size_t w2) {
    gemm_fp(srcf, w1, nullptr, hidp, M, DFF, DM, true);
    gemm_pf(hidp, w2, nullptr, kbuf, M, DM, DFF);
  };
  auto attn_self = [&](const float* srcf, int Lq, size_t wyu, const float* bout, int TK) {
    int M = B_ * Lq;
    int G8 = (Lq + 7) >> 3;
    gemm_fp(srcf, wyu, nullptr, yup, M, 512, DM, false);
    k_corr2<1, 0><<<B_, 256, 0, stream>>>(nullptr, yup, 512, srcf, nullptr, 256,
                                          wtop, dtop, Lq, Lq, TK);
    k_gather5<1><<<B_ * G8, 256, 0, stream>>>(yup + 256, 512, wtop, dtop, q, nullptr, bout,
                                              Lq, Lq, TK, G8);
  };
  auto attn_cross = [&](size_t wq2, size_t wkv, size_t wo2, const float* bq,
                        const float* bkv, const float* bo, int TK) {
    int G8 = (LD + 7) >> 3;
    gemm_fp(dec, wq2, bq, qxp, MD, DM, DM, false);
    gemm_fp(enc, wkv, bkv, yup, ME, 512, DM, false);
    k_corr2<1, 1><<<B_, 256, 0, stream>>>(nullptr, qxp, 256, nullptr, yup, 512,
                                          wtop, dtop, LD, LE, TK);
    k_gather5<0><<<B_ * G8, 256, 0, stream>>>(yup + 256, 512, wtop, dtop, nullptr, gthp, nullptr,
                                              LD, LE, TK, G8);
    gemm_pf(gthp, wo2, bo, q, MD, DM, DM);
  };

  // ---- preprocess + embeddings ----
  k_pre<<<B_, 128, 0, stream>>>(x, spad, trend);
  k_conv3<<<B_, 256, 0, stream>>>(x, we_enc, enc, LE);
  k_conv3<<<B_, 256, 0, stream>>>(spad, we_dec, dec, LD);

  // ---- encoder ----
  for (int i = 0; i < 2; ++i) {
    size_t e = enc_base(i);
    attn_self(enc, LE, e + 0, biasb + (size_t)i * 256, 13);
    k_decomp<0><<<4 * B_, 256, 0, stream>>>(enc, q, enc, nullptr, LE);
    ffn(enc, ME, e + 131072, e + 393216);
    k_decomp<0><<<4 * B_, 256, 0, stream>>>(enc, kbuf, enc, nullptr, LE);
  }
  k_lnorm<<<B_, 256, 0, stream>>>(enc, enc_g, enc, LE);

  // ---- decoder ----
  for (int i = 0; i < 2; ++i) {
    size_t d = dec_base(i);
    size_t b_ = (size_t)i * DM;
    const float* Wt_i = dWt + (size_t)i * 5 * DM * 3;
    attn_self(dec, LD, d + 0, biasb + (size_t)(2 + i) * 256, 14);
    k_decomp<1><<<4 * B_, 256, 0, stream>>>(dec, q, dec, kbuf, LD);
    k_trendconv<<<B_, 256, 0, stream>>>(kbuf, Wt_i, trend, LD);
    attn_cross(d + 131072, d + 196608, d + 327680, cbq + b_, biasb + 1024 + (size_t)i * 512, cbo + b_, 14);
    k_decomp<1><<<4 * B_, 256, 0, stream>>>(dec, q, dec, kbuf, LD);
    k_trendconv<<<B_, 256, 0, stream>>>(kbuf, Wt_i, trend, LD);
    ffn(dec, MD, d + 393216, d + 655360);
    k_decomp<1><<<4 * B_, 256, 0, stream>>>(dec, kbuf, dec, q, LD);
    k_trendconv<<<B_, 256, 0, stream>>>(q, Wt_i, trend, LD);
  }
  k_lnorm<<<B_, 256, 0, stream>>>(dec, dec_g, dec, LD);

  // ---- output head ----
  k_final<<<B_, 256, 0, stream>>>(dec, trend, projW, projb, bng, bnb, bnrm, bnrv, fcW, fcb, outp);
}